// Round 1
// baseline (150563.904 us; speedup 1.0000x reference)
//
#include <hip/hip_runtime.h>
#include <math.h>

// DummyRNN: single sequential scan over 20480 scalar inputs.
//   h_{t+1} = tanh(x_t * w_ih + b_ih + W_hh @ h_t + b_hh)
//   y_t     = W_out @ h_{t+1} + b_out
// Strictly sequential (tanh) -> persistent kernel, one device barrier/step.

#define H      1024
#define TSTEPS 20480
#define NWG    64          // workgroups; each owns H/NWG rows of W_hh
#define ROWS   16          // H / NWG
#define BLOCK  256         // 4 waves
#define RPW    4           // rows per wave (ROWS / 4 waves)

__global__ __launch_bounds__(BLOCK)
void rnn_persistent(const float* __restrict__ xs,
                    const float* __restrict__ W_ih,
                    const float* __restrict__ b_ih,
                    const float* __restrict__ W_hh,
                    const float* __restrict__ b_hh,
                    const float* __restrict__ W_out,
                    const float* __restrict__ b_out,
                    float* __restrict__ y,          // d_out, pre-zeroed
                    unsigned int* __restrict__ cnt, // ws, zeroed (monotone barrier)
                    float* __restrict__ hbuf)       // ws+256, 2*H floats, zeroed
{
    __shared__ float sW[ROWS][H];     // 64 KB: this WG's W_hh rows
    __shared__ float sYpart[BLOCK/64];

    const int tid  = threadIdx.x;
    const int wg   = blockIdx.x;
    const int wave = tid >> 6;
    const int lane = tid & 63;
    const int row0 = wg * ROWS;

    // ---- one-time preload of the W_hh slice into LDS (coalesced float4) ----
    {
        const float4* src = (const float4*)(W_hh + (size_t)row0 * H);
        float4* dst = (float4*)&sW[0][0];
        #pragma unroll
        for (int i = 0; i < (ROWS * H / 4) / BLOCK; ++i)
            dst[tid + i * BLOCK] = src[tid + i * BLOCK];
    }
    // per-row constants (identical across lanes of the wave -> stays in SGPR/VGPR)
    float wih[RPW], cb[RPW], wout[RPW];
    #pragma unroll
    for (int r = 0; r < RPW; ++r) {
        const int gr = row0 + wave * RPW + r;
        wih[r]  = W_ih[gr];              // W_ih is (H,1) flat
        cb[r]   = b_ih[gr] + b_hh[gr];
        wout[r] = W_out[gr];             // W_out is (1,H) flat
    }
    const float bout = (wg == 0) ? b_out[0] : 0.0f;
    __syncthreads();

    for (int t = 0; t < TSTEPS; ++t) {
        const float* hin  = hbuf + ((t)     & 1) * H;
        float*       hout = hbuf + ((t + 1) & 1) * H;

        // this lane's contiguous 16-element chunk of h (64B/lane, coalesced)
        float hr[16];
        {
            const float4* hp = (const float4*)(hin + lane * 16);
            #pragma unroll
            for (int q = 0; q < 4; ++q) {
                const float4 v = hp[q];
                hr[q * 4 + 0] = v.x; hr[q * 4 + 1] = v.y;
                hr[q * 4 + 2] = v.z; hr[q * 4 + 3] = v.w;
            }
        }
        const float x = xs[t];

        // 4 row-dots per wave: 16 MACs/lane from LDS, then 6-step butterfly
        float z[RPW];
        #pragma unroll
        for (int r = 0; r < RPW; ++r) {
            const float* wrow = &sW[wave * RPW + r][lane * 16];
            float acc = 0.0f;
            #pragma unroll
            for (int k = 0; k < 16; ++k) acc = fmaf(wrow[k], hr[k], acc);
            #pragma unroll
            for (int off = 32; off > 0; off >>= 1)
                acc += __shfl_xor(acc, off);
            z[r] = acc;   // fully reduced in every lane
        }

        // tanh computed redundantly in all lanes (static reg indexing, no scratch)
        float hv[RPW];
        float yp = 0.0f;
        #pragma unroll
        for (int r = 0; r < RPW; ++r) {
            hv[r] = tanhf(fmaf(x, wih[r], cb[r] + z[r]));
            yp = fmaf(wout[r], hv[r], yp);
        }
        if (lane == 0) {
            const int gr = row0 + wave * RPW;
            hout[gr + 0] = hv[0];
            hout[gr + 1] = hv[1];
            hout[gr + 2] = hv[2];
            hout[gr + 3] = hv[3];
            sYpart[wave] = yp;
        }

        // ---- device-wide barrier (release h_new, then monotone counter) ----
        __threadfence();   // release: hout stores visible at agent scope
        __syncthreads();   // sYpart ready; all waves of this WG arrived
        if (tid == 0) {
            const float ysum = sYpart[0] + sYpart[1] + sYpart[2] + sYpart[3] + bout;
            atomicAdd(&y[t], ysum);               // fire-and-forget
            atomicAdd(cnt, 1u);                   // device-scope arrive
            const unsigned target = (unsigned)(t + 1) * NWG;
            while (__hip_atomic_load(cnt, __ATOMIC_ACQUIRE,
                                     __HIP_MEMORY_SCOPE_AGENT) < target)
                __builtin_amdgcn_s_sleep(1);
        }
        __syncthreads();   // whole WG released; acquire-inv done by tid 0
    }
}

extern "C" void kernel_launch(void* const* d_in, const int* in_sizes, int n_in,
                              void* d_out, int out_size, void* d_ws, size_t ws_size,
                              hipStream_t stream) {
    const float* xs    = (const float*)d_in[0];  // input_seq (2048*10,)
    const float* W_ih  = (const float*)d_in[1];  // (1024,1)
    const float* b_ih  = (const float*)d_in[2];  // (1024,)
    const float* W_hh  = (const float*)d_in[3];  // (1024,1024)
    const float* b_hh  = (const float*)d_in[4];  // (1024,)
    const float* W_out = (const float*)d_in[5];  // (1,1024)
    const float* b_out = (const float*)d_in[6];  // (1,)
    float* y = (float*)d_out;                    // (20480,) fp32

    unsigned int* cnt = (unsigned int*)d_ws;
    float* hbuf = (float*)((char*)d_ws + 256);

    // zero barrier counter + both h buffers + output accumulator
    hipMemsetAsync(d_ws, 0, 256 + 2 * H * sizeof(float), stream);
    hipMemsetAsync(d_out, 0, (size_t)out_size * sizeof(float), stream);

    rnn_persistent<<<NWG, BLOCK, 0, stream>>>(xs, W_ih, b_ih, W_hh, b_hh,
                                              W_out, b_out, y, cnt, hbuf);
}

// Round 2
// 126092.896 us; speedup vs baseline: 1.1941x; 1.1941x over previous
//
#include <hip/hip_runtime.h>
#include <math.h>

// DummyRNN: strictly sequential scan, 20480 steps of
//   h = tanh(x_t*w_ih + b_ih + W_hh@h + b_hh);  y_t = W_out@h + b_out
// Persistent kernel, fence-free LLC synchronization:
//   - h published via relaxed agent-scope atomics (write-through L2 -> LLC)
//   - per-WAVE monotone sequence flags (256 slots, no atomic contention)
//   - no __syncthreads / no threadfence / no L2 wb-inv in the step loop

#define H       1024
#define TSTEPS  20480
#define NWG     64          // workgroups; WG owns 16 rows of W_hh
#define BLOCK   256         // 4 waves/WG -> 256 waves total
#define RPW     4           // rows per wave
#define FSTRIDE 8           // dwords per flag slot (32B)

__device__ __forceinline__ float agent_ld(const float* p) {
    return __hip_atomic_load(p, __ATOMIC_RELAXED, __HIP_MEMORY_SCOPE_AGENT);
}
__device__ __forceinline__ void agent_st(float* p, float v) {
    __hip_atomic_store(p, v, __ATOMIC_RELAXED, __HIP_MEMORY_SCOPE_AGENT);
}

__global__ __launch_bounds__(BLOCK)
void rnn_persistent(const float* __restrict__ xs,
                    const float* __restrict__ W_ih,
                    const float* __restrict__ b_ih,
                    const float* __restrict__ W_hh,
                    const float* __restrict__ b_hh,
                    const float* __restrict__ W_out,
                    const float* __restrict__ b_out,
                    float* __restrict__ y,            // d_out, zeroed
                    unsigned int* __restrict__ flags, // ws: 256 slots * 32B, zeroed
                    float* __restrict__ hbuf)         // ws+8K: 2*H floats, zeroed
{
    __shared__ float sW[16][H];   // 64 KB: this WG's 16 rows of W_hh

    const int tid  = threadIdx.x;
    const int wg   = blockIdx.x;
    const int wave = tid >> 6;
    const int lane = tid & 63;
    const int wid  = wg * 4 + wave;    // global wave id 0..255
    const int gr0  = wid * RPW;        // first of this wave's 4 rows

    // ---- one-time W_hh slice preload (coalesced float4) ----
    {
        const float4* src = (const float4*)(W_hh + (size_t)wg * 16 * H);
        float4* dst = (float4*)&sW[0][0];
        #pragma unroll
        for (int i = 0; i < (16 * H / 4) / BLOCK; ++i)
            dst[tid + i * BLOCK] = src[tid + i * BLOCK];
    }
    float wih[RPW], cb[RPW], wout[RPW];
    #pragma unroll
    for (int r = 0; r < RPW; ++r) {
        wih[r]  = W_ih[gr0 + r];
        cb[r]   = b_ih[gr0 + r] + b_hh[gr0 + r];
        wout[r] = W_out[gr0 + r];
    }
    const float bout = (wid == 0) ? b_out[0] : 0.0f;
    __syncthreads();   // sW ready (once, outside the step loop)

    for (int t = 0; t < TSTEPS; ++t) {
        const float* hin  = hbuf + ((t)     & 1) * H;
        float*       hout = hbuf + ((t + 1) & 1) * H;

        // ---- wait until all 256 waves have finished step t-1 ----
        if (t) {
            const unsigned tt = (unsigned)t;
            bool ok;
            do {
                unsigned v0 = __hip_atomic_load(&flags[(lane      ) * FSTRIDE], __ATOMIC_RELAXED, __HIP_MEMORY_SCOPE_AGENT);
                unsigned v1 = __hip_atomic_load(&flags[(lane +  64) * FSTRIDE], __ATOMIC_RELAXED, __HIP_MEMORY_SCOPE_AGENT);
                unsigned v2 = __hip_atomic_load(&flags[(lane + 128) * FSTRIDE], __ATOMIC_RELAXED, __HIP_MEMORY_SCOPE_AGENT);
                unsigned v3 = __hip_atomic_load(&flags[(lane + 192) * FSTRIDE], __ATOMIC_RELAXED, __HIP_MEMORY_SCOPE_AGENT);
                ok = (v0 >= tt) & (v1 >= tt) & (v2 >= tt) & (v3 >= tt);
            } while (!__all(ok));
            asm volatile("" ::: "memory");   // no reordering of h loads above the poll
        }

        // ---- read h from LLC: lane l owns cols 256q + 4l .. +3 (coalesced) ----
        float hr[16];
        #pragma unroll
        for (int q = 0; q < 4; ++q)
            #pragma unroll
            for (int j = 0; j < 4; ++j)
                hr[q * 4 + j] = agent_ld(hin + 256 * q + 4 * lane + j);

        const float x = xs[t];

        // ---- 4 row-dots: conflict-free ds_read_b128, butterfly reduce ----
        float z[RPW];
        #pragma unroll
        for (int r = 0; r < RPW; ++r) {
            const float* wrow = &sW[wave * RPW + r][0];
            float acc = 0.0f;
            #pragma unroll
            for (int q = 0; q < 4; ++q) {
                const float4 w = *(const float4*)&wrow[256 * q + 4 * lane];
                acc = fmaf(w.x, hr[q * 4 + 0], acc);
                acc = fmaf(w.y, hr[q * 4 + 1], acc);
                acc = fmaf(w.z, hr[q * 4 + 2], acc);
                acc = fmaf(w.w, hr[q * 4 + 3], acc);
            }
            #pragma unroll
            for (int off = 32; off > 0; off >>= 1)
                acc += __shfl_xor(acc, off);
            z[r] = acc;           // identical in all 64 lanes
        }

        float hv[RPW];
        float yp = 0.0f;
        #pragma unroll
        for (int r = 0; r < RPW; ++r) {
            hv[r] = tanhf(fmaf(x, wih[r], cb[r] + z[r]));
            yp = fmaf(wout[r], hv[r], yp);
        }

        // ---- publish: h stores (write-through LLC), vmcnt flush, flag ----
        if (lane == 0) {
            agent_st(&hout[gr0 + 0], hv[0]);
            agent_st(&hout[gr0 + 1], hv[1]);
            agent_st(&hout[gr0 + 2], hv[2]);
            agent_st(&hout[gr0 + 3], hv[3]);
        }
        asm volatile("s_waitcnt vmcnt(0)" ::: "memory");  // h at LLC before flag
        if (lane == 0) {
            __hip_atomic_store(&flags[wid * FSTRIDE], (unsigned)(t + 1),
                               __ATOMIC_RELAXED, __HIP_MEMORY_SCOPE_AGENT);
            atomicAdd(&y[t], yp + bout);   // off critical path, per-t address
        }
    }
}

extern "C" void kernel_launch(void* const* d_in, const int* in_sizes, int n_in,
                              void* d_out, int out_size, void* d_ws, size_t ws_size,
                              hipStream_t stream) {
    const float* xs    = (const float*)d_in[0];
    const float* W_ih  = (const float*)d_in[1];
    const float* b_ih  = (const float*)d_in[2];
    const float* W_hh  = (const float*)d_in[3];
    const float* b_hh  = (const float*)d_in[4];
    const float* W_out = (const float*)d_in[5];
    const float* b_out = (const float*)d_in[6];
    float* y = (float*)d_out;

    unsigned int* flags = (unsigned int*)d_ws;              // 256*32B = 8KB
    float* hbuf = (float*)((char*)d_ws + 8192);             // 2*H floats

    hipMemsetAsync(d_ws, 0, 8192 + 2 * H * sizeof(float), stream);
    hipMemsetAsync(d_out, 0, (size_t)out_size * sizeof(float), stream);

    rnn_persistent<<<NWG, BLOCK, 0, stream>>>(xs, W_ih, b_ih, W_hh, b_hh,
                                              W_out, b_out, y, flags, hbuf);
}

// Round 3
// 124682.056 us; speedup vs baseline: 1.2076x; 1.0113x over previous
//
#include <hip/hip_runtime.h>
#include <math.h>

// DummyRNN: strictly sequential scan, 20480 steps of
//   h = tanh(x_t*w_ih + b_ih + W_hh@h + b_hh);  y_t = W_out@h + b_out
//
// Persistent kernel. Synchronization is LL-style self-validating 8-byte
// pairs {float h, uint seq} stored/loaded with 64-bit relaxed agent-scope
// atomics (single-copy atomic, bypass L1/L2 to the coherent LLC). The load
// that observes seq==t already carries the h value -> ONE LLC round trip
// per step on the critical path. No barriers, no fences, no atomic RMW,
// no LDS in the step loop. W_hh lives entirely in registers.

#define H       1024
#define TSTEPS  20480
#define NWG     64          // 64 WGs x 4 waves = 256 waves, 4 rows each
#define BLOCK   256
#define RPW     4

typedef unsigned long long u64;

__device__ __forceinline__ u64 pair_ld(const u64* p) {
    return __hip_atomic_load(p, __ATOMIC_RELAXED, __HIP_MEMORY_SCOPE_AGENT);
}
__device__ __forceinline__ void pair_st(u64* p, u64 v) {
    __hip_atomic_store(p, v, __ATOMIC_RELAXED, __HIP_MEMORY_SCOPE_AGENT);
}

__global__ __launch_bounds__(BLOCK)
void rnn_persistent(const float* __restrict__ xs,
                    const float* __restrict__ W_ih,
                    const float* __restrict__ b_ih,
                    const float* __restrict__ W_hh,
                    const float* __restrict__ b_hh,
                    const float* __restrict__ W_out,
                    const float* __restrict__ b_out,
                    float* __restrict__ y,      // d_out (20480,), every elem written
                    u64* __restrict__ slots)    // ws: 2*H pairs, zeroed
{
    const int tid  = threadIdx.x;
    const int wave = tid >> 6;
    const int lane = tid & 63;
    const int wid  = blockIdx.x * 4 + wave;   // 0..255
    const int gr0  = wid * RPW;               // this wave's 4 rows

    // ---- W_hh rows in registers: wreg[r][q] = W_hh[gr0+r][256q+4l .. +3] ----
    float4 wreg[RPW][4];
    #pragma unroll
    for (int r = 0; r < RPW; ++r)
        #pragma unroll
        for (int q = 0; q < 4; ++q)
            wreg[r][q] = *(const float4*)&W_hh[(size_t)(gr0 + r) * H + 256 * q + 4 * lane];

    float wih[RPW], cb[RPW];
    #pragma unroll
    for (int r = 0; r < RPW; ++r) {
        wih[r] = W_ih[gr0 + r];
        cb[r]  = b_ih[gr0 + r] + b_hh[gr0 + r];
    }
    // y-weights for this lane's 16 columns (used by wave 0 only)
    float wo[16];
    #pragma unroll
    for (int q = 0; q < 4; ++q)
        #pragma unroll
        for (int j = 0; j < 4; ++j)
            wo[q * 4 + j] = W_out[256 * q + 4 * lane + j];
    const float bo = b_out[0];

    float hr[16];

    // poll the 16 pairs this lane consumes until all carry seq==t; data rides along
    auto poll_load = [&](int t) {
        const u64* sin = slots + (size_t)(t & 1) * H;
        u64 v[16];
        bool ok;
        do {
            ok = true;
            #pragma unroll
            for (int q = 0; q < 4; ++q)
                #pragma unroll
                for (int j = 0; j < 4; ++j)
                    v[q * 4 + j] = pair_ld(&sin[256 * q + 4 * lane + j]);
            #pragma unroll
            for (int k = 0; k < 16; ++k)
                ok &= ((unsigned)(v[k] >> 32) == (unsigned)t);
        } while (!__all(ok));
        #pragma unroll
        for (int k = 0; k < 16; ++k)
            hr[k] = __uint_as_float((unsigned)v[k]);
    };

    for (int t = 0; t < TSTEPS; ++t) {
        poll_load(t);                       // hr = h_t (step 0: zeros, seq 0 preset)

        const float x = xs[t];

        // 4 row-dots: 16 FMA/lane from registers + 6-step butterfly
        float z[RPW];
        #pragma unroll
        for (int r = 0; r < RPW; ++r) {
            float acc = 0.0f;
            #pragma unroll
            for (int q = 0; q < 4; ++q) {
                const float4 w = wreg[r][q];
                acc = fmaf(w.x, hr[q * 4 + 0], acc);
                acc = fmaf(w.y, hr[q * 4 + 1], acc);
                acc = fmaf(w.z, hr[q * 4 + 2], acc);
                acc = fmaf(w.w, hr[q * 4 + 3], acc);
            }
            #pragma unroll
            for (int off = 32; off > 0; off >>= 1)
                acc += __shfl_xor(acc, off);
            z[r] = acc;                     // full dot, all lanes
        }

        float hv[RPW];
        #pragma unroll
        for (int r = 0; r < RPW; ++r)
            hv[r] = tanhf(fmaf(x, wih[r], cb[r] + z[r]));

        // publish h_{t+1}: 4 self-validating pairs, fire-and-forget
        {
            u64* sout = slots + (size_t)((t + 1) & 1) * H;
            const u64 tag = (u64)(unsigned)(t + 1) << 32;
            if (lane == 0) {
                pair_st(&sout[gr0 + 0], tag | __float_as_uint(hv[0]));
                pair_st(&sout[gr0 + 1], tag | __float_as_uint(hv[1]));
                pair_st(&sout[gr0 + 2], tag | __float_as_uint(hv[2]));
                pair_st(&sout[gr0 + 3], tag | __float_as_uint(hv[3]));
            }
        }

        // y[t-1] = W_out @ h_t + b_out : wave 0 only, AFTER publish (hidden)
        if (wid == 0 && t > 0) {
            float acc = 0.0f;
            #pragma unroll
            for (int k = 0; k < 16; ++k) acc = fmaf(wo[k], hr[k], acc);
            #pragma unroll
            for (int off = 32; off > 0; off >>= 1)
                acc += __shfl_xor(acc, off);
            if (lane == 0) y[t - 1] = acc + bo;
        }
    }

    // tail: y[TSTEPS-1] from h_TSTEPS
    if (wid == 0) {
        poll_load(TSTEPS);
        float acc = 0.0f;
        #pragma unroll
        for (int k = 0; k < 16; ++k) acc = fmaf(wo[k], hr[k], acc);
        #pragma unroll
        for (int off = 32; off > 0; off >>= 1)
            acc += __shfl_xor(acc, off);
        if (lane == 0) y[TSTEPS - 1] = acc + bo;
    }
}

extern "C" void kernel_launch(void* const* d_in, const int* in_sizes, int n_in,
                              void* d_out, int out_size, void* d_ws, size_t ws_size,
                              hipStream_t stream) {
    const float* xs    = (const float*)d_in[0];
    const float* W_ih  = (const float*)d_in[1];
    const float* b_ih  = (const float*)d_in[2];
    const float* W_hh  = (const float*)d_in[3];
    const float* b_hh  = (const float*)d_in[4];
    const float* W_out = (const float*)d_in[5];
    const float* b_out = (const float*)d_in[6];
    float* y   = (float*)d_out;
    u64* slots = (u64*)d_ws;                 // 2*H pairs = 16 KB

    // parity-0 slots = {h=0, seq=0} (valid step-0 input); parity-1 seq=0 != 1
    hipMemsetAsync(d_ws, 0, 2 * H * sizeof(u64), stream);

    rnn_persistent<<<NWG, BLOCK, 0, stream>>>(xs, W_ih, b_ih, W_hh, b_hh,
                                              W_out, b_out, y, slots);
}

// Round 4
// 69172.333 us; speedup vs baseline: 2.1766x; 1.8025x over previous
//
#include <hip/hip_runtime.h>
#include <math.h>

// DummyRNN: strictly sequential scan, 20480 steps of
//   h = tanh(x_t*w_ih + b_ih + W_hh@h + b_hh);  y_t = W_out@h + b_out
//
// Persistent kernel, LL-style {f32 h, u32 seq} pairs in LLC. KEY CHANGE vs R3:
// the poll reads the pairs with inline-asm global_load_dwordx4 sc0 sc1
// (bypass L1/L2 -> coherent LLC, but lane-coalesced into 128B line requests)
// instead of per-lane 8B atomic loads (which hit the uncoalesced atomic path:
// 262K requests/sweep was the 6us/step floor). Publish remains 4 narrow
// agent-scope 8B atomic stores per wave. No fences, no RMW, no LDS.

#define H       1024
#define TSTEPS  20480
#define NWG     64          // 64 WGs x 4 waves = 256 waves, 4 rows each
#define BLOCK   256
#define RPW     4

typedef unsigned long long u64;
typedef unsigned int u32x4 __attribute__((ext_vector_type(4)));

__device__ __forceinline__ void pair_st(u64* p, u64 v) {
    __hip_atomic_store(p, v, __ATOMIC_RELAXED, __HIP_MEMORY_SCOPE_AGENT);
}

__global__ __launch_bounds__(BLOCK)
void rnn_persistent(const float* __restrict__ xs,
                    const float* __restrict__ W_ih,
                    const float* __restrict__ b_ih,
                    const float* __restrict__ W_hh,
                    const float* __restrict__ b_hh,
                    const float* __restrict__ W_out,
                    const float* __restrict__ b_out,
                    float* __restrict__ y,      // d_out (20480,), every elem written
                    u64* __restrict__ slots)    // ws: 2*H pairs, zeroed
{
    const int tid  = threadIdx.x;
    const int wave = tid >> 6;
    const int lane = tid & 63;
    const int wid  = blockIdx.x * 4 + wave;   // 0..255
    const int gr0  = wid * RPW;               // this wave's 4 rows

    // lane l consumes h-columns c(j,i) = 128*j + 2*l + i, j=0..7, i=0..1
    // (pair-index = column; 16B/lane, lane-contiguous per instruction j)
    float2 wreg[RPW][8];
    #pragma unroll
    for (int r = 0; r < RPW; ++r)
        #pragma unroll
        for (int j = 0; j < 8; ++j)
            wreg[r][j] = *(const float2*)&W_hh[(size_t)(gr0 + r) * H + 128 * j + 2 * lane];

    float wih[RPW], cb[RPW];
    #pragma unroll
    for (int r = 0; r < RPW; ++r) {
        wih[r] = W_ih[gr0 + r];
        cb[r]  = b_ih[gr0 + r] + b_hh[gr0 + r];
    }
    float2 wo2[8];
    #pragma unroll
    for (int j = 0; j < 8; ++j)
        wo2[j] = *(const float2*)&W_out[128 * j + 2 * lane];
    const float bo = b_out[0];

    float hr[16];

    // poll this lane's 16 pairs until every tag == t; data rides along.
    // 8x global_load_dwordx4 sc0 sc1 (LLC, coalesced) + vmcnt(0) in ONE asm.
    auto poll_load = [&](int t) {
        const u64* sin = slots + (size_t)(t & 1) * H;
        const char* a0 = (const char*)(sin + 2 * lane);  // pairs 2l,2l+1 (+128j)
        const char* a1 = a0 + 4096;                      // j = 4..7
        const unsigned tt = (unsigned)t;
        u32x4 L0, L1, L2, L3, L4, L5, L6, L7;
        bool ok;
        do {
            asm volatile(
                "global_load_dwordx4 %0, %8, off sc0 sc1\n\t"
                "global_load_dwordx4 %1, %8, off offset:1024 sc0 sc1\n\t"
                "global_load_dwordx4 %2, %8, off offset:2048 sc0 sc1\n\t"
                "global_load_dwordx4 %3, %8, off offset:3072 sc0 sc1\n\t"
                "global_load_dwordx4 %4, %9, off sc0 sc1\n\t"
                "global_load_dwordx4 %5, %9, off offset:1024 sc0 sc1\n\t"
                "global_load_dwordx4 %6, %9, off offset:2048 sc0 sc1\n\t"
                "global_load_dwordx4 %7, %9, off offset:3072 sc0 sc1\n\t"
                "s_waitcnt vmcnt(0)"
                : "=&v"(L0), "=&v"(L1), "=&v"(L2), "=&v"(L3),
                  "=&v"(L4), "=&v"(L5), "=&v"(L6), "=&v"(L7)
                : "v"(a0), "v"(a1)
                : "memory");
            ok = (L0[1] == tt) & (L0[3] == tt) & (L1[1] == tt) & (L1[3] == tt)
               & (L2[1] == tt) & (L2[3] == tt) & (L3[1] == tt) & (L3[3] == tt)
               & (L4[1] == tt) & (L4[3] == tt) & (L5[1] == tt) & (L5[3] == tt)
               & (L6[1] == tt) & (L6[3] == tt) & (L7[1] == tt) & (L7[3] == tt);
        } while (!__all(ok));
        hr[ 0] = __uint_as_float(L0[0]); hr[ 1] = __uint_as_float(L0[2]);
        hr[ 2] = __uint_as_float(L1[0]); hr[ 3] = __uint_as_float(L1[2]);
        hr[ 4] = __uint_as_float(L2[0]); hr[ 5] = __uint_as_float(L2[2]);
        hr[ 6] = __uint_as_float(L3[0]); hr[ 7] = __uint_as_float(L3[2]);
        hr[ 8] = __uint_as_float(L4[0]); hr[ 9] = __uint_as_float(L4[2]);
        hr[10] = __uint_as_float(L5[0]); hr[11] = __uint_as_float(L5[2]);
        hr[12] = __uint_as_float(L6[0]); hr[13] = __uint_as_float(L6[2]);
        hr[14] = __uint_as_float(L7[0]); hr[15] = __uint_as_float(L7[2]);
    };

    for (int t = 0; t < TSTEPS; ++t) {
        poll_load(t);                       // hr = h_t (step 0: zeros, tag 0)

        const float x = xs[t];

        float z[RPW];
        #pragma unroll
        for (int r = 0; r < RPW; ++r) {
            float acc = 0.0f;
            #pragma unroll
            for (int j = 0; j < 8; ++j) {
                acc = fmaf(wreg[r][j].x, hr[2 * j + 0], acc);
                acc = fmaf(wreg[r][j].y, hr[2 * j + 1], acc);
            }
            #pragma unroll
            for (int off = 32; off > 0; off >>= 1)
                acc += __shfl_xor(acc, off);
            z[r] = acc;                     // full dot, all lanes
        }

        float hv[RPW];
        #pragma unroll
        for (int r = 0; r < RPW; ++r)
            hv[r] = tanhf(fmaf(x, wih[r], cb[r] + z[r]));

        // publish h_{t+1}: lanes 0..3 store one self-validating pair each
        {
            u64* sout = slots + (size_t)((t + 1) & 1) * H;
            const u64 tag = (u64)(unsigned)(t + 1) << 32;
            float hvm = hv[0];                       // static-index select
            hvm = (lane == 1) ? hv[1] : hvm;
            hvm = (lane == 2) ? hv[2] : hvm;
            hvm = (lane == 3) ? hv[3] : hvm;
            if (lane < RPW)
                pair_st(&sout[gr0 + lane], tag | (u64)__float_as_uint(hvm));
        }

        // y[t-1] = W_out @ h_t + b_out : wave 0 only, AFTER publish
        if (wid == 0 && t > 0) {
            float acc = 0.0f;
            #pragma unroll
            for (int j = 0; j < 8; ++j) {
                acc = fmaf(wo2[j].x, hr[2 * j + 0], acc);
                acc = fmaf(wo2[j].y, hr[2 * j + 1], acc);
            }
            #pragma unroll
            for (int off = 32; off > 0; off >>= 1)
                acc += __shfl_xor(acc, off);
            if (lane == 0) y[t - 1] = acc + bo;
        }
    }

    // tail: y[TSTEPS-1] from h_TSTEPS
    if (wid == 0) {
        poll_load(TSTEPS);
        float acc = 0.0f;
        #pragma unroll
        for (int j = 0; j < 8; ++j) {
            acc = fmaf(wo2[j].x, hr[2 * j + 0], acc);
            acc = fmaf(wo2[j].y, hr[2 * j + 1], acc);
        }
        #pragma unroll
        for (int off = 32; off > 0; off >>= 1)
            acc += __shfl_xor(acc, off);
        if (lane == 0) y[TSTEPS - 1] = acc + bo;
    }
}

extern "C" void kernel_launch(void* const* d_in, const int* in_sizes, int n_in,
                              void* d_out, int out_size, void* d_ws, size_t ws_size,
                              hipStream_t stream) {
    const float* xs    = (const float*)d_in[0];
    const float* W_ih  = (const float*)d_in[1];
    const float* b_ih  = (const float*)d_in[2];
    const float* W_hh  = (const float*)d_in[3];
    const float* b_hh  = (const float*)d_in[4];
    const float* W_out = (const float*)d_in[5];
    const float* b_out = (const float*)d_in[6];
    float* y   = (float*)d_out;
    u64* slots = (u64*)d_ws;                 // 2*H pairs = 16 KB

    // parity-0 slots = {h=0, tag=0} (valid step-0 input); parity-1 tag=0 != 1
    hipMemsetAsync(d_ws, 0, 2 * H * sizeof(u64), stream);

    rnn_persistent<<<NWG, BLOCK, 0, stream>>>(xs, W_ih, b_ih, W_hh, b_hh,
                                              W_out, b_out, y, slots);
}